// Round 5
// baseline (720.841 us; speedup 1.0000x reference)
//
#include <hip/hip_runtime.h>
#include <hip/hip_bf16.h>
#include <stdint.h>

// x[8192,4096] f32, qw[4096,4096] f32 in {-1,+1}, bias[4096] f32
#define B_DIM   8192
#define IN_DIM  4096
#define OUT_DIM 4096
#define QB_V    128.0f
#define EPS_V   1e-5f
// out-group: 512 rows = 2^21 elems ; batch-group: 1024 rows = 2^22 elems

typedef __attribute__((ext_vector_type(4))) float  f32x4;
typedef __attribute__((ext_vector_type(8))) __bf16 bf16x8;

__device__ __forceinline__ void gload_lds16(const void* g, void* l) {
  void* gp = const_cast<void*>(g);
  __builtin_amdgcn_global_load_lds(
      (__attribute__((address_space(1))) void*)gp,
      (__attribute__((address_space(3))) void*)l, 16, 0, 0);
}

__device__ __forceinline__ __bf16 sgnb(float d) {
  return (__bf16)((d > 0.f) ? 1.f : (d < 0.f ? -1.f : 0.f));
}

// ---- zero scratch header: sums[8] f32 + gamma_bits[8] u32 ----
__global__ void k_init(unsigned* ws) {
  int t = threadIdx.x;
  if (t < 16) ws[t] = 0u;
}

// ---- per-out-group sum of |qw| (integer-valued -> exact f32 atomics) ----
__global__ __launch_bounds__(256) void k_qw_sums(const float* __restrict__ qw,
                                                 float* __restrict__ sums) {
  __shared__ float red[4];
  const int t = threadIdx.x;
  for (int vb = blockIdx.x; vb < 4096; vb += 2048) {
    const size_t base = (size_t)vb * 4096;
    float s = 0.f;
#pragma unroll
    for (int j = 0; j < 4; ++j) {
      f32x4 v = *(const f32x4*)(qw + base + (size_t)j * 1024 + t * 4);
      s += fabsf(v.x) + fabsf(v.y) + fabsf(v.z) + fabsf(v.w);
    }
#pragma unroll
    for (int off = 32; off > 0; off >>= 1) s += __shfl_xor(s, off);
    __syncthreads();
    if ((t & 63) == 0) red[t >> 6] = s;
    __syncthreads();
    if (t == 0)
      atomicAdd(sums + (vb >> 9), red[0] + red[1] + red[2] + red[3]);
  }
}

// ---- merged: bw = sign(qw - mu_g) bf16 (vb 0..4095) ; x -> bf16 (4096..12287) ----
__global__ __launch_bounds__(256) void k_conv(const float* __restrict__ qw,
                                              const float* __restrict__ sums,
                                              __bf16* __restrict__ bw,
                                              const float* __restrict__ x,
                                              __bf16* __restrict__ xb) {
  const int t = threadIdx.x;
  for (int vb = blockIdx.x; vb < 12288; vb += 2048) {
    if (vb < 4096) {
      const size_t i = ((size_t)vb * 256 + t) * 16;
      const float mu = sums[(int)(i >> 21)] * (1.0f / 2097152.0f);
#pragma unroll
      for (int h = 0; h < 2; ++h) {
        f32x4 v0 = *(const f32x4*)(qw + i + h * 8);
        f32x4 v1 = *(const f32x4*)(qw + i + h * 8 + 4);
        bf16x8 r;
        r[0] = sgnb(v0.x - mu); r[1] = sgnb(v0.y - mu);
        r[2] = sgnb(v0.z - mu); r[3] = sgnb(v0.w - mu);
        r[4] = sgnb(v1.x - mu); r[5] = sgnb(v1.y - mu);
        r[6] = sgnb(v1.z - mu); r[7] = sgnb(v1.w - mu);
        *(bf16x8*)(bw + i + h * 8) = r;
      }
    } else {
      const size_t i = ((size_t)(vb - 4096) * 256 + t) * 16;
#pragma unroll
      for (int h = 0; h < 2; ++h) {
        f32x4 v0 = *(const f32x4*)(x + i + h * 8);
        f32x4 v1 = *(const f32x4*)(x + i + h * 8 + 4);
        bf16x8 r;
        r[0] = (__bf16)v0.x; r[1] = (__bf16)v0.y;
        r[2] = (__bf16)v0.z; r[3] = (__bf16)v0.w;
        r[4] = (__bf16)v1.x; r[5] = (__bf16)v1.y;
        r[6] = (__bf16)v1.z; r[7] = (__bf16)v1.w;
        *(bf16x8*)(xb + i + h * 8) = r;
      }
    }
  }
}

// ---- GEMM 256x256 tile, BK=32, 512 thr = 8 waves (2Mx4N), 128x64/wave ----
// Ring of 4 LDS buffers (128 KB total). While computing tile kt, stage tile
// kt+3 into slot (kt+3)&3 (= slot of kt-1, whose reads ended at the previous
// boundary barrier). Tile boundary: s_waitcnt vmcnt(8) (tiles kt+2,kt+3 = 8
// loads/wave stay in flight; every wave confirming its own loads + barrier
// => whole tile landed for all waves). Two phases/tile, 16-MFMA clusters
// with setprio (T5); af frags reused across both phases. T2 chunk-swizzle:
// LDS chunk c of row r holds global chunk c ^ ((r>>1)&3) (64 B rows, 16 B
// chunks) -> fragment reads spread 64 lanes uniformly over banks.
__global__ __launch_bounds__(512, 2) void k_gemm256(
    const __bf16* __restrict__ xa, const __bf16* __restrict__ bwb,
    const float* __restrict__ bias, float* __restrict__ out,
    unsigned* __restrict__ gamma_bits) {
  __shared__ __bf16 As[4][256 * 32];
  __shared__ __bf16 Bs[4][256 * 32];
  const int t = threadIdx.x;
  const int lane = t & 63;
  const int wv = t >> 6;
  const int wr = wv >> 2;         // 0..1 (M half)
  const int wc = wv & 3;          // 0..3 (N quarter)
  const int fr = lane & 15, fq = lane >> 4;
  const int swz8 = (fq ^ ((fr >> 1) & 3)) << 3;   // elem offset of 16B chunk

  // XCD-aware bijective swizzle: grid=512, 512%8==0
  const int orig = blockIdx.x;
  const int bid = ((orig & 7) << 6) | (orig >> 3);
  const int bm = bid & 31, bn = bid >> 5;
  const int brow = bm << 8, bcol = bn << 8;

  // staging: thread t covers row t>>2 (and +128), chunk t&3; source chunk
  // pre-swizzled so the linear global_load_lds dest lands swizzled (rule 21)
  const int srow = t >> 2;
  const int schunk8 = ((t & 3) ^ ((t >> 3) & 3)) << 3;
  const int doff0 = t * 8;                  // == srow*32 + (t&3)*8 elems
  const int doff1 = doff0 + 128 * 32;
  const __bf16* aR0 = xa + (size_t)(brow + srow) * IN_DIM + schunk8;
  const __bf16* aR1 = aR0 + (size_t)128 * IN_DIM;
  const __bf16* bR0 = bwb + (size_t)(bcol + srow) * IN_DIM + schunk8;
  const __bf16* bR1 = bR0 + (size_t)128 * IN_DIM;

#define STAGE_A(kt, sl)                          \
  {                                              \
    const int _k = (kt) << 5;                    \
    gload_lds16(aR0 + _k, &As[sl][doff0]);       \
    gload_lds16(aR1 + _k, &As[sl][doff1]);       \
  }
#define STAGE_B(kt, sl)                          \
  {                                              \
    const int _k = (kt) << 5;                    \
    gload_lds16(bR0 + _k, &Bs[sl][doff0]);       \
    gload_lds16(bR1 + _k, &Bs[sl][doff1]);       \
  }

  f32x4 acc[8][4] = {};

#define TILE_BODY(kt, sl, DOSTAGE)                                            \
  {                                                                           \
    bf16x8 af[8], bf01[2], bf23[2];                                           \
    if (DOSTAGE) STAGE_A((kt) + 3, ((kt) + 3) & 3);                           \
    _Pragma("unroll") for (int m = 0; m < 8; ++m)                             \
        af[m] = *(const bf16x8*)(&As[sl][((wr << 7) + (m << 4) + fr) * 32 +   \
                                         swz8]);                              \
    _Pragma("unroll") for (int n = 0; n < 2; ++n)                             \
        bf01[n] = *(const bf16x8*)(&Bs[sl][((wc << 6) + (n << 4) + fr) * 32 + \
                                           swz8]);                            \
    __builtin_amdgcn_s_barrier();                                             \
    __builtin_amdgcn_s_setprio(1);                                            \
    _Pragma("unroll") for (int m = 0; m < 8; ++m)                             \
      _Pragma("unroll") for (int n = 0; n < 2; ++n)                           \
          acc[m][n] = __builtin_amdgcn_mfma_f32_16x16x32_bf16(                \
              af[m], bf01[n], acc[m][n], 0, 0, 0);                            \
    __builtin_amdgcn_s_setprio(0);                                            \
    __builtin_amdgcn_s_barrier();                                             \
    if (DOSTAGE) STAGE_B((kt) + 3, ((kt) + 3) & 3);                           \
    _Pragma("unroll") for (int n = 0; n < 2; ++n)                             \
        bf23[n] = *(const bf16x8*)(&Bs[sl][((wc << 6) + ((n + 2) << 4) + fr) *\
                                               32 + swz8]);                   \
    __builtin_amdgcn_s_barrier();                                             \
    __builtin_amdgcn_s_setprio(1);                                            \
    _Pragma("unroll") for (int m = 0; m < 8; ++m)                             \
      _Pragma("unroll") for (int n = 0; n < 2; ++n)                           \
          acc[m][n + 2] = __builtin_amdgcn_mfma_f32_16x16x32_bf16(            \
              af[m], bf23[n], acc[m][n + 2], 0, 0, 0);                        \
    __builtin_amdgcn_s_setprio(0);                                            \
  }
#define BOUNDARY(N)                                        \
  asm volatile("s_waitcnt vmcnt(" #N ")" ::: "memory");    \
  __builtin_amdgcn_s_barrier();

  // prologue: tiles 0,1,2 -> slots 0,1,2 (12 loads); wait tile 0 (8 in flight)
  STAGE_A(0, 0); STAGE_B(0, 0);
  STAGE_A(1, 1); STAGE_B(1, 1);
  STAGE_A(2, 2); STAGE_B(2, 2);
  BOUNDARY(8)

  for (int ktb = 0; ktb < 124; ktb += 4) {
#pragma unroll
    for (int u = 0; u < 4; ++u) {
      TILE_BODY(ktb + u, u, true)
      BOUNDARY(8)
    }
  }
  // tail: kt = 124..127 (slots 0..3); 124 stages tile 127; drain 8->4->0
  TILE_BODY(124, 0, true)
  BOUNDARY(8)
  TILE_BODY(125, 1, false)
  BOUNDARY(4)
  TILE_BODY(126, 2, false)
  BOUNDARY(0)
  TILE_BODY(127, 3, false)

#undef STAGE_A
#undef STAGE_B
#undef TILE_BODY
#undef BOUNDARY

  // epilogue: +bias, store f32, fused per-batch-group abs-max
  float mx = 0.f;
  const int colbase = bcol + (wc << 6);
#pragma unroll
  for (int n = 0; n < 4; ++n) {
    const int col = colbase + (n << 4) + fr;
    const float bv = bias[col];
#pragma unroll
    for (int m = 0; m < 8; ++m) {
      const int rowb = brow + (wr << 7) + (m << 4) + (fq << 2);
#pragma unroll
      for (int j = 0; j < 4; ++j) {
        const float v = acc[m][n][j] + bv;
        out[(size_t)(rowb + j) * OUT_DIM + col] = v;
        mx = fmaxf(mx, fabsf(v));
      }
    }
  }
#pragma unroll
  for (int off = 32; off > 0; off >>= 1) mx = fmaxf(mx, __shfl_xor(mx, off));
  if (lane == 0)
    atomicMax(gamma_bits + (brow >> 10), __float_as_uint(mx));
}

// ---- q = clip(out * 128/(gamma_g+eps), -128+eps, 128-eps), in place ----
__global__ __launch_bounds__(256) void k_scale(float* __restrict__ out,
                                               const unsigned* __restrict__ gb) {
  const int t = threadIdx.x;
  for (int vb = blockIdx.x; vb < 8192; vb += 2048) {
    const size_t i = ((size_t)vb * 256 + t) * 16;
    const float gamma = __uint_as_float(gb[(int)(i >> 22)]);
    const float sc = QB_V / (gamma + EPS_V);
    const float lo = -QB_V + EPS_V, hi = QB_V - EPS_V;
#pragma unroll
    for (int h = 0; h < 4; ++h) {
      f32x4 v = *(const f32x4*)(out + i + h * 4);
      v.x = fminf(fmaxf(v.x * sc, lo), hi);
      v.y = fminf(fmaxf(v.y * sc, lo), hi);
      v.z = fminf(fmaxf(v.z * sc, lo), hi);
      v.w = fminf(fmaxf(v.w * sc, lo), hi);
      *(f32x4*)(out + i + h * 4) = v;
    }
  }
}

extern "C" void kernel_launch(void* const* d_in, const int* in_sizes, int n_in,
                              void* d_out, int out_size, void* d_ws,
                              size_t ws_size, hipStream_t stream) {
  const float* x = (const float*)d_in[0];
  const float* qw = (const float*)d_in[1];
  const float* bias = (const float*)d_in[2];
  float* out = (float*)d_out;
  char* ws = (char*)d_ws;
  float* sums = (float*)ws;                    // 8 x f32
  unsigned* gamma = (unsigned*)ws + 8;         // 8 x u32 (f32 bits, >=0)
  __bf16* bwb = (__bf16*)(ws + 256);                                   // 32 MB
  __bf16* xb = (__bf16*)(ws + 256 + (size_t)OUT_DIM * IN_DIM * 2);     // 64 MB

  k_init<<<1, 64, 0, stream>>>((unsigned*)ws);
  k_qw_sums<<<2048, 256, 0, stream>>>(qw, sums);
  k_conv<<<2048, 256, 0, stream>>>(qw, sums, bwb, x, xb);
  k_gemm256<<<512, 512, 0, stream>>>(xb, bwb, bias, out, gamma);
  k_scale<<<2048, 256, 0, stream>>>(out, gamma);
}

// Round 6
// 691.616 us; speedup vs baseline: 1.0423x; 1.0423x over previous
//
#include <hip/hip_runtime.h>
#include <hip/hip_bf16.h>
#include <stdint.h>

// x[8192,4096] f32, qw[4096,4096] f32 in {-1,+1}, bias[4096] f32
#define B_DIM   8192
#define IN_DIM  4096
#define OUT_DIM 4096
#define QB_V    128.0f
#define EPS_V   1e-5f
// out-group: 512 rows = 2^21 elems ; batch-group: 1024 rows = 2^22 elems

typedef __attribute__((ext_vector_type(4))) float  f32x4;
typedef __attribute__((ext_vector_type(8))) __bf16 bf16x8;

__device__ __forceinline__ void gload_lds16(const void* g, void* l) {
  void* gp = const_cast<void*>(g);
  __builtin_amdgcn_global_load_lds(
      (__attribute__((address_space(1))) void*)gp,
      (__attribute__((address_space(3))) void*)l, 16, 0, 0);
}

__device__ __forceinline__ __bf16 sgnb(float d) {
  return (__bf16)((d > 0.f) ? 1.f : (d < 0.f ? -1.f : 0.f));
}

// ---- zero scratch header: sums[8] f32 + gamma_bits[8] u32 ----
__global__ void k_init(unsigned* ws) {
  int t = threadIdx.x;
  if (t < 16) ws[t] = 0u;
}

// ---- per-out-group sum of |qw| (integer-valued -> exact f32 atomics) ----
__global__ __launch_bounds__(256) void k_qw_sums(const float* __restrict__ qw,
                                                 float* __restrict__ sums) {
  __shared__ float red[4];
  const int t = threadIdx.x;
  for (int vb = blockIdx.x; vb < 4096; vb += 2048) {
    const size_t base = (size_t)vb * 4096;
    float s = 0.f;
#pragma unroll
    for (int j = 0; j < 4; ++j) {
      f32x4 v = *(const f32x4*)(qw + base + (size_t)j * 1024 + t * 4);
      s += fabsf(v.x) + fabsf(v.y) + fabsf(v.z) + fabsf(v.w);
    }
#pragma unroll
    for (int off = 32; off > 0; off >>= 1) s += __shfl_xor(s, off);
    __syncthreads();
    if ((t & 63) == 0) red[t >> 6] = s;
    __syncthreads();
    if (t == 0)
      atomicAdd(sums + (vb >> 9), red[0] + red[1] + red[2] + red[3]);
  }
}

// ---- merged: bw = sign(qw - mu_g) bf16 (vb 0..4095) ; x -> bf16 (4096..12287) ----
__global__ __launch_bounds__(256) void k_conv(const float* __restrict__ qw,
                                              const float* __restrict__ sums,
                                              __bf16* __restrict__ bw,
                                              const float* __restrict__ x,
                                              __bf16* __restrict__ xb) {
  const int t = threadIdx.x;
  for (int vb = blockIdx.x; vb < 12288; vb += 2048) {
    if (vb < 4096) {
      const size_t i = ((size_t)vb * 256 + t) * 16;
      const float mu = sums[(int)(i >> 21)] * (1.0f / 2097152.0f);
#pragma unroll
      for (int h = 0; h < 2; ++h) {
        f32x4 v0 = *(const f32x4*)(qw + i + h * 8);
        f32x4 v1 = *(const f32x4*)(qw + i + h * 8 + 4);
        bf16x8 r;
        r[0] = sgnb(v0.x - mu); r[1] = sgnb(v0.y - mu);
        r[2] = sgnb(v0.z - mu); r[3] = sgnb(v0.w - mu);
        r[4] = sgnb(v1.x - mu); r[5] = sgnb(v1.y - mu);
        r[6] = sgnb(v1.z - mu); r[7] = sgnb(v1.w - mu);
        *(bf16x8*)(bw + i + h * 8) = r;
      }
    } else {
      const size_t i = ((size_t)(vb - 4096) * 256 + t) * 16;
#pragma unroll
      for (int h = 0; h < 2; ++h) {
        f32x4 v0 = *(const f32x4*)(x + i + h * 8);
        f32x4 v1 = *(const f32x4*)(x + i + h * 8 + 4);
        bf16x8 r;
        r[0] = (__bf16)v0.x; r[1] = (__bf16)v0.y;
        r[2] = (__bf16)v0.z; r[3] = (__bf16)v0.w;
        r[4] = (__bf16)v1.x; r[5] = (__bf16)v1.y;
        r[6] = (__bf16)v1.z; r[7] = (__bf16)v1.w;
        *(bf16x8*)(xb + i + h * 8) = r;
      }
    }
  }
}

// ---- GEMM 256x256 tile, BK=32, 512 thr = 8 waves (2Mx4N), 128x64/wave ----
// Ring of 4 LDS buffers (128 KB). While computing tile kt, stage tile kt+3
// into slot (kt+3)&3 (slot freed at the previous boundary barrier). ONE sync
// point per tile: s_waitcnt vmcnt(8) + s_barrier (8 loads/wave for tiles
// kt+2,kt+3 stay in flight; tail drains 8->4->0; never vmcnt(0) mid-loop).
// NO intra-tile barriers: fragments live in registers, ring slots are
// protected by the boundary alone, so waves drift within the tile window and
// ds_read/stage issue overlaps other waves' MFMA clusters (m114 overlap).
// setprio(1) biases the scheduler toward MFMA-phase waves (T5). T2 chunk
// swizzle: LDS chunk c of row r holds global chunk c ^ ((r>>1)&3) (64 B rows,
// 16 B chunks); staged with pre-swizzled global source, linear LDS dest.
__global__ __launch_bounds__(512, 2) void k_gemm256(
    const __bf16* __restrict__ xa, const __bf16* __restrict__ bwb,
    const float* __restrict__ bias, float* __restrict__ out,
    unsigned* __restrict__ gamma_bits) {
  __shared__ __bf16 As[4][256 * 32];
  __shared__ __bf16 Bs[4][256 * 32];
  const int t = threadIdx.x;
  const int lane = t & 63;
  const int wv = t >> 6;
  const int wr = wv >> 2;         // 0..1 (M half)
  const int wc = wv & 3;          // 0..3 (N quarter)
  const int fr = lane & 15, fq = lane >> 4;
  const int swz8 = (fq ^ ((fr >> 1) & 3)) << 3;   // elem offset of 16B chunk

  // XCD-aware bijective swizzle: grid=512, 512%8==0
  const int orig = blockIdx.x;
  const int bid = ((orig & 7) << 6) | (orig >> 3);
  const int bm = bid & 31, bn = bid >> 5;
  const int brow = bm << 8, bcol = bn << 8;

  // staging: thread t covers row t>>2 (and +128), chunk t&3; source chunk
  // pre-swizzled so the linear global_load_lds dest lands swizzled (rule 21)
  const int srow = t >> 2;
  const int schunk8 = ((t & 3) ^ ((t >> 3) & 3)) << 3;
  const int doff0 = t * 8;                  // == srow*32 + (t&3)*8 elems
  const int doff1 = doff0 + 128 * 32;
  const __bf16* aR0 = xa + (size_t)(brow + srow) * IN_DIM + schunk8;
  const __bf16* aR1 = aR0 + (size_t)128 * IN_DIM;
  const __bf16* bR0 = bwb + (size_t)(bcol + srow) * IN_DIM + schunk8;
  const __bf16* bR1 = bR0 + (size_t)128 * IN_DIM;

#define STAGE_A(kt, sl)                          \
  {                                              \
    const int _k = (kt) << 5;                    \
    gload_lds16(aR0 + _k, &As[sl][doff0]);       \
    gload_lds16(aR1 + _k, &As[sl][doff1]);       \
  }
#define STAGE_B(kt, sl)                          \
  {                                              \
    const int _k = (kt) << 5;                    \
    gload_lds16(bR0 + _k, &Bs[sl][doff0]);       \
    gload_lds16(bR1 + _k, &Bs[sl][doff1]);       \
  }

  f32x4 acc[8][4] = {};

  // Tile body, no internal barriers: 12 ds_read -> stage(kt+3) -> 32 MFMA.
#define TILE_BODY(kt, sl, DOSTAGE)                                            \
  {                                                                           \
    bf16x8 af[8], bfv[4];                                                     \
    _Pragma("unroll") for (int m = 0; m < 8; ++m)                             \
        af[m] = *(const bf16x8*)(&As[sl][((wr << 7) + (m << 4) + fr) * 32 +   \
                                         swz8]);                              \
    _Pragma("unroll") for (int n = 0; n < 4; ++n)                             \
        bfv[n] = *(const bf16x8*)(&Bs[sl][((wc << 6) + (n << 4) + fr) * 32 +  \
                                          swz8]);                             \
    if (DOSTAGE) {                                                            \
      STAGE_A((kt) + 3, ((kt) + 3) & 3);                                      \
      STAGE_B((kt) + 3, ((kt) + 3) & 3);                                      \
    }                                                                         \
    __builtin_amdgcn_s_setprio(1);                                            \
    _Pragma("unroll") for (int m = 0; m < 8; ++m)                             \
      _Pragma("unroll") for (int n = 0; n < 4; ++n)                           \
          acc[m][n] = __builtin_amdgcn_mfma_f32_16x16x32_bf16(                \
              af[m], bfv[n], acc[m][n], 0, 0, 0);                             \
    __builtin_amdgcn_s_setprio(0);                                            \
  }
#define BOUNDARY(N)                                        \
  asm volatile("s_waitcnt vmcnt(" #N ")" ::: "memory");    \
  __builtin_amdgcn_s_barrier();

  // prologue: tiles 0,1,2 -> slots 0,1,2 (12 loads); wait tile 0 (8 in flight)
  STAGE_A(0, 0); STAGE_B(0, 0);
  STAGE_A(1, 1); STAGE_B(1, 1);
  STAGE_A(2, 2); STAGE_B(2, 2);
  BOUNDARY(8)

  for (int ktb = 0; ktb < 124; ktb += 4) {
#pragma unroll
    for (int u = 0; u < 4; ++u) {
      TILE_BODY(ktb + u, u, true)
      BOUNDARY(8)
    }
  }
  // tail: kt = 124..127 (slots 0..3); 124 stages tile 127; drain 8->4->0
  TILE_BODY(124, 0, true)
  BOUNDARY(8)
  TILE_BODY(125, 1, false)
  BOUNDARY(4)
  TILE_BODY(126, 2, false)
  BOUNDARY(0)
  TILE_BODY(127, 3, false)

#undef STAGE_A
#undef STAGE_B
#undef TILE_BODY
#undef BOUNDARY

  // epilogue: +bias, store f32, fused per-batch-group abs-max
  float mx = 0.f;
  const int colbase = bcol + (wc << 6);
#pragma unroll
  for (int n = 0; n < 4; ++n) {
    const int col = colbase + (n << 4) + fr;
    const float bv = bias[col];
#pragma unroll
    for (int m = 0; m < 8; ++m) {
      const int rowb = brow + (wr << 7) + (m << 4) + (fq << 2);
#pragma unroll
      for (int j = 0; j < 4; ++j) {
        const float v = acc[m][n][j] + bv;
        out[(size_t)(rowb + j) * OUT_DIM + col] = v;
        mx = fmaxf(mx, fabsf(v));
      }
    }
  }
#pragma unroll
  for (int off = 32; off > 0; off >>= 1) mx = fmaxf(mx, __shfl_xor(mx, off));
  if (lane == 0)
    atomicMax(gamma_bits + (brow >> 10), __float_as_uint(mx));
}

// ---- q = clip(out * 128/(gamma_g+eps), -128+eps, 128-eps), in place ----
__global__ __launch_bounds__(256) void k_scale(float* __restrict__ out,
                                               const unsigned* __restrict__ gb) {
  const int t = threadIdx.x;
  for (int vb = blockIdx.x; vb < 8192; vb += 2048) {
    const size_t i = ((size_t)vb * 256 + t) * 16;
    const float gamma = __uint_as_float(gb[(int)(i >> 22)]);
    const float sc = QB_V / (gamma + EPS_V);
    const float lo = -QB_V + EPS_V, hi = QB_V - EPS_V;
#pragma unroll
    for (int h = 0; h < 4; ++h) {
      f32x4 v = *(const f32x4*)(out + i + h * 4);
      v.x = fminf(fmaxf(v.x * sc, lo), hi);
      v.y = fminf(fmaxf(v.y * sc, lo), hi);
      v.z = fminf(fmaxf(v.z * sc, lo), hi);
      v.w = fminf(fmaxf(v.w * sc, lo), hi);
      *(f32x4*)(out + i + h * 4) = v;
    }
  }
}

extern "C" void kernel_launch(void* const* d_in, const int* in_sizes, int n_in,
                              void* d_out, int out_size, void* d_ws,
                              size_t ws_size, hipStream_t stream) {
  const float* x = (const float*)d_in[0];
  const float* qw = (const float*)d_in[1];
  const float* bias = (const float*)d_in[2];
  float* out = (float*)d_out;
  char* ws = (char*)d_ws;
  float* sums = (float*)ws;                    // 8 x f32
  unsigned* gamma = (unsigned*)ws + 8;         // 8 x u32 (f32 bits, >=0)
  __bf16* bwb = (__bf16*)(ws + 256);                                   // 32 MB
  __bf16* xb = (__bf16*)(ws + 256 + (size_t)OUT_DIM * IN_DIM * 2);     // 64 MB

  k_init<<<1, 64, 0, stream>>>((unsigned*)ws);
  k_qw_sums<<<2048, 256, 0, stream>>>(qw, sums);
  k_conv<<<2048, 256, 0, stream>>>(qw, sums, bwb, x, xb);
  k_gemm256<<<512, 512, 0, stream>>>(xb, bwb, bias, out, gamma);
  k_scale<<<2048, 256, 0, stream>>>(out, gamma);
}